// Round 5
// baseline (303.179 us; speedup 1.0000x reference)
//
#include <hip/hip_runtime.h>
#include <stdint.h>

typedef unsigned short ushort_t;
typedef _Float16 f16x8 __attribute__((ext_vector_type(8)));
typedef float f32x4 __attribute__((ext_vector_type(4)));
typedef float f32x16 __attribute__((ext_vector_type(16)));
typedef int   i32x4 __attribute__((ext_vector_type(4)));
typedef int   i32x16 __attribute__((ext_vector_type(16)));
typedef unsigned int uint4v __attribute__((ext_vector_type(4)));

#define HW_ 16384
#define MFMAH  __builtin_amdgcn_mfma_f32_32x32x16_f16
#define MFMAI8 __builtin_amdgcn_mfma_i32_32x32x32_i8
#define C_CORR (1.0f/16777216.0f)   // 2^-24: Al8(2^15)*Wh8(2^9) and Ah8(2^4)*Wl8(2^20)

__device__ __forceinline__ ushort_t f2h_bits(float f){
  union { _Float16 h; ushort_t u; } c; c.h = (_Float16)f; return c.u;
}
__device__ __forceinline__ float h_bits2f(ushort_t u){
  union { _Float16 h; ushort_t u; } c; c.u = u; return (float)c.h;
}
__device__ __forceinline__ int clamp8(int v){ return min(max(v,-127),127); }

// ---------------------------------------------------------------------------
// WpH (f16 bits): ((conv*2+mh)*36 + ks16)*512 + lane*8 + j
//   conv 0=Ws 1=Wx 2=Wy; co = mh*32+(lane&31); tap = ks16>>2;
//   ci = (ks16&3)*16 + (lane>>5)*8 + j.
// WpC (i8 dwords): ((g*2+mh)*18 + ks32)*256 + lane*4 + j4
//   g 0=Wh8x 1=Wh8y 2=Wl8x 3=Wl8y; tap = ks32>>1;
//   ci = (ks32&1)*32 + (lane>>5)*16 + j4*4 + bb.
// ---------------------------------------------------------------------------
__global__ __launch_bounds__(256) void k_repack(
    const float* __restrict__ Ws, const float* __restrict__ Wx,
    const float* __restrict__ Wy,
    ushort_t* __restrict__ WpH, unsigned int* __restrict__ WpC){
  int e = blockIdx.x*256 + threadIdx.x;
  if (e < 110592){
    int j = e & 7; int lane = (e >> 3) & 63; int rest = e >> 9;
    int ks = rest % 36; int cm = rest / 36;
    int conv = cm >> 1; int mh = cm & 1;
    int co = mh*32 + (lane & 31);
    int tap = ks >> 2;
    int ci = (ks & 3)*16 + ((lane >> 5) & 1)*8 + j;
    const float* src = (conv==0) ? Ws : (conv==1) ? Wx : Wy;
    WpH[e] = f2h_bits(src[(co*64 + ci)*9 + tap]);
  } else if (e < 110592 + 36864){
    int d = e - 110592;
    int j4 = d & 3; int lane = (d >> 2) & 63; int rest = d >> 8;
    int ks = rest % 18; int gm = rest / 18;
    int g = gm >> 1; int mh = gm & 1;
    int co = mh*32 + (lane & 31);
    int tap = ks >> 1;
    const float* src = (g==0 || g==2) ? Wx : Wy;
    unsigned dd = 0;
    #pragma unroll
    for (int bb=0; bb<4; bb++){
      int ci = (ks & 1)*32 + ((lane >> 5) & 1)*16 + j4*4 + bb;
      float w = src[(co*64 + ci)*9 + tap];
      int v;
      if (g < 2){
        v = clamp8((int)rintf(w*512.f));
      } else {
        float wl = w - h_bits2f(f2h_bits(w));
        v = clamp8((int)rintf(wl*1048576.f));
      }
      dd |= ((unsigned)(v & 255)) << (bb*8);
    }
    WpC[d] = dd;
  }
}

// ---------------------------------------------------------------------------
// Fused conv, occupancy-first restructure (R4 post-mortem: 155us at 27%
// MfmaUtil was per-iteration load-latency stall at only ~2 waves/SIMD; MFMA
// floor is 38us).  12-wave WG (768 thr), wave = (conv 0..2) x (mh) x (row):
//   - per-wave acc: 16 regs (score) / 32 regs (gx,gy) vs 160 before
//   - arch regs ~60-100 -> occupancy wave-slot-limited: 2 blocks/CU =
//     24 waves/CU (6/SIMD, 3x previous) for latency hiding
//   - total MFMA count unchanged; B-frags shared via same LDS tile
//   - gx/gy combine avoided: x-wave stores low u16 of coords word, y-wave
//     stores high u16 (bit-identical packed value, no exchange)
//   - 1-deep register prefetch of next-ks weights (clamped ptr), unroll 2
// WG tile: 2 h-rows x 32 w. LDS: BH f16 [4r][34][64] oct-swizzle ^(w1&7);
// BAl/BAh i8 same grid, slot (q+(w1>>1))&3. 34816 B (x2 blocks = 70KB/CU).
// Grid 4096 XCD-swizzled: all WGs of batch b on XCD b&7.
// ---------------------------------------------------------------------------
__global__ __launch_bounds__(768, 3) void k_conv_all(
    const float* __restrict__ x,
    const ushort_t* __restrict__ WpH, const unsigned int* __restrict__ WpC,
    const float* __restrict__ bs, const float* __restrict__ bx,
    const float* __restrict__ by,
    ushort_t* __restrict__ score, unsigned int* __restrict__ coords){
  int bid = blockIdx.x;
  int idx = bid >> 3;
  int b = (bid & 7) + 8*(idx >> 8);     // 256 blocks per batch
  int rest = idx & 255;
  int h0 = (rest >> 2)*2;               // 64 h-tiles of 2 rows
  int wq = (rest & 3)*32;
  int t = threadIdx.x; int lane = t & 63; int wid = t >> 6;   // wid 0..11
  int n = lane & 31; int kh = lane >> 5;
  __shared__ __align__(16) _Float16 BH[4*34*64];   // 17408 B
  __shared__ __align__(16) char BAl[4*34*64];      //  8704 B
  __shared__ __align__(16) char BAh[4*34*64];      //  8704 B

  // ---- staging: 544 items of 16 ci; one item per thread (544 < 768) ----
  const float* xb = x + (size_t)b*64*HW_;
  if (t < 544){
    int f = t;
    int r = f/136; int rem = f - r*136; int q = rem/34; int w1 = rem - q*34;
    int y = h0 + r - 1; int w = wq + w1 - 1;
    f16x8 h0v = {0,0,0,0,0,0,0,0}, h1v = {0,0,0,0,0,0,0,0};
    unsigned alb[4] = {0,0,0,0}, ahb[4] = {0,0,0,0};
    if (((unsigned)y < 128u) & ((unsigned)w < 128u)){
      const float* p = xb + (size_t)(q*16)*HW_ + y*128 + w;
      #pragma unroll
      for (int j=0; j<16; j++){
        float v = p[(size_t)j*HW_];
        _Float16 hv = (_Float16)v;
        float al = v - (float)hv;
        int a8 = clamp8((int)rintf(al*32768.f));
        int x8 = clamp8((int)rintf(v*16.f));
        if (j < 8) h0v[j] = hv; else h1v[j-8] = hv;
        alb[j>>2] |= ((unsigned)(a8 & 255)) << ((j&3)*8);
        ahb[j>>2] |= ((unsigned)(x8 & 255)) << ((j&3)*8);
      }
    }
    int base = (r*34 + w1)*64;
    int sw = w1 & 7;
    *(f16x8*)&BH[base + (((2*q)   ^ sw) << 3)] = h0v;
    *(f16x8*)&BH[base + (((2*q+1) ^ sw) << 3)] = h1v;
    int islot = ((q + (w1 >> 1)) & 3) << 4;
    i32x4 av  = {(int)alb[0],(int)alb[1],(int)alb[2],(int)alb[3]};
    i32x4 hv2 = {(int)ahb[0],(int)ahb[1],(int)ahb[2],(int)ahb[3]};
    *(i32x4*)&BAl[base + islot] = av;
    *(i32x4*)&BAh[base + islot] = hv2;
  }
  __syncthreads();

  int conv   = wid >> 2;     // 0=score 1=gx 2=gy
  int sub    = wid & 3;
  int mh     = sub & 1;      // co half
  int row_id = sub >> 1;     // h row within tile

  int w = wq + n;
  int h = h0 + row_id;
  size_t obase = (size_t)b*64*HW_ + (size_t)h*128 + w;

  if (conv == 0){
    // ------------------ score wave: f16 MFMA only ------------------
    f32x16 acc;
    #pragma unroll
    for (int r2=0; r2<16; r2++) acc[r2]=0.f;
    const ushort_t* pF = WpH + ((0*2+mh)*36)*512 + lane*8;
    f16x8 w0 = *(const f16x8*)pF;
    f16x8 w1v = *(const f16x8*)(pF + 512);
    #pragma unroll 2
    for (int ks=0; ks<18; ++ks){
      int tap = ks >> 1; int qp = ks & 1;
      int rb = (tap*11) >> 5;            // tap/3 for tap in [0,8]
      int dw = tap - rb*3 - 1;
      int wc = n + dw + 1;               // 0..33
      int sw = wc & 7;
      int rowb = ((rb + row_id)*34 + wc)*64;
      int off0 = ((qp*4 + kh)     ^ sw) << 3;
      int off1 = ((qp*4 + 2 + kh) ^ sw) << 3;
      f16x8 bA = *(const f16x8*)&BH[rowb + off0];
      f16x8 bB = *(const f16x8*)&BH[rowb + off1];
      int adv = (ks < 17) ? 1024 : 0;    // clamp: stay in-bounds on last iter
      f16x8 n0 = *(const f16x8*)(pF + adv);
      f16x8 n1 = *(const f16x8*)(pF + adv + 512);
      acc = MFMAH(w0,  bA, acc, 0,0,0);
      acc = MFMAH(w1v, bB, acc, 0,0,0);
      w0 = n0; w1v = n1; pF += adv;
    }
    #pragma unroll
    for (int reg=0; reg<16; reg++){
      int col = mh*32 + (reg & 3) + 8*(reg >> 2) + 4*kh;
      float sv = acc[reg] + bs[col];
      score[obase + (size_t)col*HW_] = f2h_bits(sv);
    }
  } else {
    // ------------------ gx / gy wave: f16 + i8 corrections ------------------
    f32x16 acc; i32x16 c;
    #pragma unroll
    for (int r2=0; r2<16; r2++){ acc[r2]=0.f; c[r2]=0; }
    const ushort_t* pF = WpH + ((conv*2+mh)*36)*512 + lane*8;
    const char* pWh = (const char*)WpC + ((((conv-1)*2+mh)*18)*64 + lane)*16;
    const char* pWl = (const char*)WpC + ((((conv+1)*2+mh)*18)*64 + lane)*16;
    f16x8 w0 = *(const f16x8*)pF;
    f16x8 w1v = *(const f16x8*)(pF + 512);
    i32x4 wh = *(const i32x4*)pWh;
    i32x4 wl = *(const i32x4*)pWl;
    #pragma unroll 2
    for (int ks=0; ks<18; ++ks){
      int tap = ks >> 1; int qp = ks & 1;
      int rb = (tap*11) >> 5;
      int dw = tap - rb*3 - 1;
      int wc = n + dw + 1;
      int sw = wc & 7;
      int rowb = ((rb + row_id)*34 + wc)*64;
      int off0 = ((qp*4 + kh)     ^ sw) << 3;
      int off1 = ((qp*4 + 2 + kh) ^ sw) << 3;
      int islot = (((qp*2 + kh) + (wc >> 1)) & 3) << 4;
      f16x8 bA  = *(const f16x8*)&BH[rowb + off0];
      f16x8 bB  = *(const f16x8*)&BH[rowb + off1];
      i32x4 bal = *(const i32x4*)&BAl[rowb + islot];
      i32x4 bah = *(const i32x4*)&BAh[rowb + islot];
      int adv = (ks < 17) ? 1024 : 0;
      f16x8 n0 = *(const f16x8*)(pF + adv);
      f16x8 n1 = *(const f16x8*)(pF + adv + 512);
      i32x4 nh = *(const i32x4*)(pWh + adv);
      i32x4 nl = *(const i32x4*)(pWl + adv);
      acc = MFMAH(w0,  bA, acc, 0,0,0);
      acc = MFMAH(w1v, bB, acc, 0,0,0);
      c = MFMAI8(wh, bal, c, 0,0,0);
      c = MFMAI8(wl, bah, c, 0,0,0);
      w0 = n0; w1v = n1; wh = nh; wl = nl;
      pF += adv; pWh += adv; pWl += adv;
    }
    const float* bias = (conv == 1) ? bx : by;
    int half = conv - 1;    // 0 -> low u16 (ux), 1 -> high u16 (uy)
    #pragma unroll
    for (int reg=0; reg<16; reg++){
      int col = mh*32 + (reg & 3) + 8*(reg >> 2) + 4*kh;
      float g = acc[reg] + (float)c[reg]*C_CORR + bias[col];
      float iz = fminf(fmaxf((g + 1.f)*64.f - 0.5f, -2.f), 129.f);
      unsigned uz = (unsigned)rintf((iz + 2.f)*480.f);
      ushort_t* cw = (ushort_t*)(coords + obase + (size_t)col*HW_);
      cw[half] = (ushort_t)uz;
    }
  }
}

// ---------------------------------------------------------------------------
// Sampler: one WG per (b,co); f16 score plane in LDS; coords/out streamed.
// Grid 1024 XCD-swizzled (matches conv's b->XCD mapping, L2-hot reads).
// ---------------------------------------------------------------------------
__global__ __launch_bounds__(256, 4) void k_sample(
    const ushort_t* __restrict__ score, const unsigned int* __restrict__ coords,
    float* __restrict__ out){
  int bid = blockIdx.x;
  int idx = bid >> 3;
  int b  = (bid & 7) + 8*(idx >> 6);
  int co = idx & 63;
  int t = threadIdx.x;
  __shared__ __align__(16) ushort_t SC[128*136];

  const ushort_t* sp = score + (size_t)(b*64 + co)*HW_;
  #pragma unroll
  for (int i=0;i<8;i++){
    int c = i*256 + t;
    int y = c >> 4; int xg = (c & 15)*8;
    *(f16x8*)&SC[y*136 + xg] = *(const f16x8*)(sp + c*8);
  }
  __syncthreads();

  const unsigned int* cp = coords + (size_t)(b*64 + co)*HW_;
  float* op = out + (size_t)(b*64 + co)*HW_;
  uint4v ca = *(const uint4v*)(cp + t*8);
  uint4v cb2 = *(const uint4v*)(cp + t*8 + 4);
  #pragma unroll 1
  for (int k=0;k<8;k++){
    int px = (k*256 + t)*8;
    uint4v na, nb;
    if (k < 7){
      na = *(const uint4v*)(cp + px + 2048);
      nb = *(const uint4v*)(cp + px + 2052);
    }
    float r[8];
    #pragma unroll
    for (int j=0;j<8;j++){
      unsigned u = (j < 4) ? ca[j] : cb2[j-4];
      float ix = (float)(u & 0xffffu)*(1.0f/480.0f) - 2.0f;
      float iy = (float)(u >> 16)   *(1.0f/480.0f) - 2.0f;
      float x0f = floorf(ix), y0f = floorf(iy);
      int x0 = (int)x0f, y0 = (int)y0f;
      float wx1 = ix - x0f, wy1 = iy - y0f;
      float wx0 = 1.f - wx1, wy0 = 1.f - wy1;
      int x0c = min(max(x0,0),127), x1c = min(max(x0+1,0),127);
      int y0c = min(max(y0,0),127), y1c = min(max(y0+1,0),127);
      bool vx0 = (unsigned)x0     < 128u, vx1 = (unsigned)(x0+1) < 128u;
      bool vy0 = (unsigned)y0     < 128u, vy1 = (unsigned)(y0+1) < 128u;
      float v00 = (vy0 && vx0) ? h_bits2f(SC[y0c*136 + x0c]) : 0.f;
      float v01 = (vy0 && vx1) ? h_bits2f(SC[y0c*136 + x1c]) : 0.f;
      float v10 = (vy1 && vx0) ? h_bits2f(SC[y1c*136 + x0c]) : 0.f;
      float v11 = (vy1 && vx1) ? h_bits2f(SC[y1c*136 + x1c]) : 0.f;
      r[j] = v00*(wy0*wx0) + v01*(wy0*wx1) + v10*(wy1*wx0) + v11*(wy1*wx1);
    }
    f32x4 r0 = {r[0],r[1],r[2],r[3]};
    f32x4 r1 = {r[4],r[5],r[6],r[7]};
    *(f32x4*)(op + px)     = r0;
    *(f32x4*)(op + px + 4) = r1;
    ca = na; cb2 = nb;
  }
}

// ---------------------------------------------------------------------------
extern "C" void kernel_launch(void* const* d_in, const int* in_sizes, int n_in,
                              void* d_out, int out_size, void* d_ws, size_t ws_size,
                              hipStream_t stream){
  const float* x  = (const float*)d_in[0];
  const float* Ws = (const float*)d_in[1];
  const float* bs = (const float*)d_in[2];
  const float* Wx = (const float*)d_in[3];
  const float* bx = (const float*)d_in[4];
  const float* Wy = (const float*)d_in[5];
  const float* by = (const float*)d_in[6];
  float* out = (float*)d_out;
  ushort_t* ws  = (ushort_t*)d_ws;
  ushort_t*     score  = ws;                                   // 33.5 MB f16
  unsigned int* coords = (unsigned int*)(ws + 16777216);       // 67.1 MB u32
  ushort_t*     WpH    = ws + 50331648;                        // 221 KB
  unsigned int* WpC    = (unsigned int*)(ws + 50331648 + 110592); // 147 KB

  k_repack  <<<dim3(576),  256, 0, stream>>>(Ws, Wx, Wy, WpH, WpC);
  k_conv_all<<<dim3(4096), 768, 0, stream>>>(x, WpH, WpC, bs, bx, by, score, coords);
  k_sample  <<<dim3(1024), 256, 0, stream>>>(score, coords, out);
}

// Round 6
// 279.173 us; speedup vs baseline: 1.0860x; 1.0860x over previous
//
#include <hip/hip_runtime.h>
#include <stdint.h>

typedef unsigned short ushort_t;
typedef _Float16 f16x8 __attribute__((ext_vector_type(8)));
typedef float f32x4 __attribute__((ext_vector_type(4)));
typedef float f32x16 __attribute__((ext_vector_type(16)));
typedef int   i32x4 __attribute__((ext_vector_type(4)));
typedef int   i32x16 __attribute__((ext_vector_type(16)));
typedef unsigned int uint4v __attribute__((ext_vector_type(4)));

#define HW_ 16384
#define MFMAH  __builtin_amdgcn_mfma_f32_32x32x16_f16
#define MFMAI8 __builtin_amdgcn_mfma_i32_32x32x32_i8
#define C_CORR (1.0f/16777216.0f)   // 2^-24: Al8(2^15)*Wh8(2^9) and Ah8(2^4)*Wl8(2^20)

__device__ __forceinline__ ushort_t f2h_bits(float f){
  union { _Float16 h; ushort_t u; } c; c.h = (_Float16)f; return c.u;
}
__device__ __forceinline__ float h_bits2f(ushort_t u){
  union { _Float16 h; ushort_t u; } c; c.u = u; return (float)c.h;
}
__device__ __forceinline__ int clamp8(int v){ return min(max(v,-127),127); }

// ---------------------------------------------------------------------------
// WpH (f16 bits): ((conv*2+mh)*36 + ks16)*512 + lane*8 + j
//   conv 0=Ws 1=Wx 2=Wy; co = mh*32+(lane&31); tap = ks16>>2;
//   ci = (ks16&3)*16 + (lane>>5)*8 + j.
// WpC (i8 dwords): ((g*2+mh)*18 + ks32)*256 + lane*4 + j4
//   g 0=Wh8x 1=Wh8y 2=Wl8x 3=Wl8y; tap = ks32>>1;
//   ci = (ks32&1)*32 + (lane>>5)*16 + j4*4 + bb.
// ---------------------------------------------------------------------------
__global__ __launch_bounds__(256) void k_repack(
    const float* __restrict__ Ws, const float* __restrict__ Wx,
    const float* __restrict__ Wy,
    ushort_t* __restrict__ WpH, unsigned int* __restrict__ WpC){
  int e = blockIdx.x*256 + threadIdx.x;
  if (e < 110592){
    int j = e & 7; int lane = (e >> 3) & 63; int rest = e >> 9;
    int ks = rest % 36; int cm = rest / 36;
    int conv = cm >> 1; int mh = cm & 1;
    int co = mh*32 + (lane & 31);
    int tap = ks >> 2;
    int ci = (ks & 3)*16 + ((lane >> 5) & 1)*8 + j;
    const float* src = (conv==0) ? Ws : (conv==1) ? Wx : Wy;
    WpH[e] = f2h_bits(src[(co*64 + ci)*9 + tap]);
  } else if (e < 110592 + 36864){
    int d = e - 110592;
    int j4 = d & 3; int lane = (d >> 2) & 63; int rest = d >> 8;
    int ks = rest % 18; int gm = rest / 18;
    int g = gm >> 1; int mh = gm & 1;
    int co = mh*32 + (lane & 31);
    int tap = ks >> 1;
    const float* src = (g==0 || g==2) ? Wx : Wy;
    unsigned dd = 0;
    #pragma unroll
    for (int bb=0; bb<4; bb++){
      int ci = (ks & 1)*32 + ((lane >> 5) & 1)*16 + j4*4 + bb;
      float w = src[(co*64 + ci)*9 + tap];
      int v;
      if (g < 2){
        v = clamp8((int)rintf(w*512.f));
      } else {
        float wl = w - h_bits2f(f2h_bits(w));
        v = clamp8((int)rintf(wl*1048576.f));
      }
      dd |= ((unsigned)(v & 255)) << (bb*8);
    }
    WpC[d] = dd;
  }
}

// ---------------------------------------------------------------------------
// Fused conv. R5 post-mortem: occupancy 21->50% bought nothing (183us) ->
// latency theory dead. Ranking R0/R4/R5 (167/155/183us) tracks L2 weight
// traffic exactly (2.95/1.47/2.95 GB): the binding resource is weight
// RE-FETCH bandwidth (L2 ~34.5 TB/s ceiling, ~50-70% sustained).
// Fix: amortize weights over 4x pixels per block. Per-wave code is
// byte-identical to R4 (2-row, 20 MFMA/iter, unroll-1, no spill); block
// grows to 8 waves (512 thr) = mh(2) x row-pair(4) on an 8-row x 32-w tile.
// Each mh weight stream now shared by 4 waves (L1 32KB holds ~3 iters of
// the 10KB/iter slice). Weight L2 traffic: 1024 blocks x 368 KB = 0.38 GB.
// LDS [10][34][64] x {f16,i8,i8} = 87 KB -> 1 block/CU = 8 waves/CU: SAME
// wave count as R4 (2x4), so latency hiding / LDS ratio / regs held equal.
// Grid 1024 XCD-swizzled: all WGs of batch b on XCD b&7.
// ---------------------------------------------------------------------------
__global__ __launch_bounds__(512, 2) void k_conv_all(
    const float* __restrict__ x,
    const ushort_t* __restrict__ WpH, const unsigned int* __restrict__ WpC,
    const float* __restrict__ bs, const float* __restrict__ bx,
    const float* __restrict__ by,
    ushort_t* __restrict__ score, unsigned int* __restrict__ coords){
  int bid = blockIdx.x;
  int idx = bid >> 3;
  int b = (bid & 7) + 8*(idx >> 6);     // 64 blocks per batch
  int rest = idx & 63;
  int h0 = (rest >> 2)*8;               // 16 h-tiles of 8 rows
  int wq = (rest & 3)*32;
  int t = threadIdx.x; int lane = t & 63; int wid = t >> 6;   // wid 0..7
  int n = lane & 31; int kh = lane >> 5;
  __shared__ __align__(16) _Float16 BH[10*34*64];   // 43520 B
  __shared__ __align__(16) char BAl[10*34*64];      // 21760 B
  __shared__ __align__(16) char BAh[10*34*64];      // 21760 B

  // ---- staging: 1360 items of 16 ci (10 rows x 4 q x 34 w1), 3 passes ----
  const float* xb = x + (size_t)b*64*HW_;
  #pragma unroll
  for (int it=0; it<3; it++){
    int f = it*512 + t;
    if (f < 1360){
      int r = f/136; int rem = f - r*136; int q = rem/34; int w1 = rem - q*34;
      int y = h0 + r - 1; int w = wq + w1 - 1;
      f16x8 h0v = {0,0,0,0,0,0,0,0}, h1v = {0,0,0,0,0,0,0,0};
      unsigned alb[4] = {0,0,0,0}, ahb[4] = {0,0,0,0};
      if (((unsigned)y < 128u) & ((unsigned)w < 128u)){
        const float* p = xb + (size_t)(q*16)*HW_ + y*128 + w;
        #pragma unroll
        for (int j=0; j<16; j++){
          float v = p[(size_t)j*HW_];
          _Float16 hv = (_Float16)v;
          float al = v - (float)hv;
          int a8 = clamp8((int)rintf(al*32768.f));
          int x8 = clamp8((int)rintf(v*16.f));
          if (j < 8) h0v[j] = hv; else h1v[j-8] = hv;
          alb[j>>2] |= ((unsigned)(a8 & 255)) << ((j&3)*8);
          ahb[j>>2] |= ((unsigned)(x8 & 255)) << ((j&3)*8);
        }
      }
      int base = (r*34 + w1)*64;
      int sw = w1 & 7;
      *(f16x8*)&BH[base + (((2*q)   ^ sw) << 3)] = h0v;
      *(f16x8*)&BH[base + (((2*q+1) ^ sw) << 3)] = h1v;
      int islot = ((q + (w1 >> 1)) & 3) << 4;
      i32x4 av  = {(int)alb[0],(int)alb[1],(int)alb[2],(int)alb[3]};
      i32x4 hv2 = {(int)ahb[0],(int)ahb[1],(int)ahb[2],(int)ahb[3]};
      *(i32x4*)&BAl[base + islot] = av;
      *(i32x4*)&BAh[base + islot] = hv2;
    }
  }
  __syncthreads();

  int mh = wid & 1;      // co half
  int pp = wid >> 1;     // row-pair within tile (0..3)

  f32x16 acc_s0, acc_gx0, acc_gy0, acc_s1, acc_gx1, acc_gy1;
  i32x16 c_x0, c_y0, c_x1, c_y1;
  #pragma unroll
  for (int r2=0; r2<16; r2++){
    acc_s0[r2]=0.f; acc_gx0[r2]=0.f; acc_gy0[r2]=0.f;
    acc_s1[r2]=0.f; acc_gx1[r2]=0.f; acc_gy1[r2]=0.f;
    c_x0[r2]=0; c_y0[r2]=0; c_x1[r2]=0; c_y1[r2]=0;
  }

  // incremented weight pointers: f16 advance 1024 elem (2 ks16) per ks-iter,
  // i8 advance 1024 B (1 ks32) per ks-iter.
  const ushort_t* pS = WpH + ((0*2+mh)*36)*512 + lane*8;
  const ushort_t* pX = WpH + ((1*2+mh)*36)*512 + lane*8;
  const ushort_t* pY = WpH + ((2*2+mh)*36)*512 + lane*8;
  const char* pWhx = (const char*)WpC + (((0*2+mh)*18)*64 + lane)*16;
  const char* pWhy = (const char*)WpC + (((1*2+mh)*18)*64 + lane)*16;
  const char* pWlx = (const char*)WpC + (((2*2+mh)*18)*64 + lane)*16;
  const char* pWly = (const char*)WpC + (((3*2+mh)*18)*64 + lane)*16;

  // one weight fetch -> MFMAs for BOTH rows of this wave's pair
  #define ROWBLK(ROWB, AS_, AX_, AY_, CX_, CY_) do {                    \
    f16x8 bA  = *(const f16x8*)&BH[(ROWB) + off0];                      \
    f16x8 bB  = *(const f16x8*)&BH[(ROWB) + off1];                      \
    i32x4 bal = *(const i32x4*)&BAl[(ROWB) + islot];                    \
    i32x4 bah = *(const i32x4*)&BAh[(ROWB) + islot];                    \
    AS_ = MFMAH(sA, bA, AS_, 0,0,0);                                    \
    AX_ = MFMAH(xA, bA, AX_, 0,0,0);                                    \
    AY_ = MFMAH(yA, bA, AY_, 0,0,0);                                    \
    AS_ = MFMAH(sB, bB, AS_, 0,0,0);                                    \
    AX_ = MFMAH(xB, bB, AX_, 0,0,0);                                    \
    AY_ = MFMAH(yB, bB, AY_, 0,0,0);                                    \
    CX_ = MFMAI8(whx, bal, CX_, 0,0,0);                                 \
    CX_ = MFMAI8(wlx, bah, CX_, 0,0,0);                                 \
    CY_ = MFMAI8(why, bal, CY_, 0,0,0);                                 \
    CY_ = MFMAI8(wly, bah, CY_, 0,0,0);                                 \
  } while(0)

  #pragma unroll 1
  for (int ks=0; ks<18; ++ks){
    int tap = ks >> 1; int qp = ks & 1;
    int rb = tap/3; int dw = tap - rb*3 - 1;
    int w1 = n + dw + 1;                    // 0..33
    int sw = w1 & 7;
    int rowb0 = ((rb + 2*pp)*34 + w1)*64;   // LDS row for output row 2*pp
    int rowb1 = rowb0 + 34*64;              // output row 2*pp+1
    int off0  = ((qp*4 + kh)     ^ sw) << 3;
    int off1  = ((qp*4 + 2 + kh) ^ sw) << 3;
    int islot = (((qp*2 + kh) + (w1 >> 1)) & 3) << 4;
    f16x8 sA = *(const f16x8*)pS;
    f16x8 sB = *(const f16x8*)(pS + 512);
    f16x8 xA = *(const f16x8*)pX;
    f16x8 xB = *(const f16x8*)(pX + 512);
    f16x8 yA = *(const f16x8*)pY;
    f16x8 yB = *(const f16x8*)(pY + 512);
    i32x4 whx = *(const i32x4*)pWhx;
    i32x4 why = *(const i32x4*)pWhy;
    i32x4 wlx = *(const i32x4*)pWlx;
    i32x4 wly = *(const i32x4*)pWly;
    ROWBLK(rowb0, acc_s0, acc_gx0, acc_gy0, c_x0, c_y0);
    ROWBLK(rowb1, acc_s1, acc_gx1, acc_gy1, c_x1, c_y1);
    pS += 1024; pX += 1024; pY += 1024;
    pWhx += 1024; pWhy += 1024; pWlx += 1024; pWly += 1024;
  }
  #undef ROWBLK

  // epilogue: score f16 + packed u16 coords (step 1/480 px, clamp [-2,129])
  int w = wq + n;
  int hb = h0 + 2*pp;
  #define EPILOG(AS_, AX_, AY_, CX_, CY_, H_) do {                      \
    ushort_t*     sb = score  + (size_t)b*64*HW_ + (H_)*128 + w;        \
    unsigned int* cb = coords + (size_t)b*64*HW_ + (H_)*128 + w;        \
    _Pragma("unroll")                                                   \
    for (int reg=0; reg<16; reg++){                                     \
      int col = mh*32 + (reg & 3) + 8*(reg >> 2) + 4*kh;                \
      float sv = AS_[reg] + bs[col];                                    \
      float gx = AX_[reg] + (float)CX_[reg]*C_CORR + bx[col];           \
      float gy = AY_[reg] + (float)CY_[reg]*C_CORR + by[col];           \
      sb[(size_t)col*HW_] = f2h_bits(sv);                               \
      float ixf = fminf(fmaxf((gx + 1.f)*64.f - 0.5f, -2.f), 129.f);    \
      float iyf = fminf(fmaxf((gy + 1.f)*64.f - 0.5f, -2.f), 129.f);    \
      unsigned ux = (unsigned)rintf((ixf + 2.f)*480.f);                 \
      unsigned uy = (unsigned)rintf((iyf + 2.f)*480.f);                 \
      cb[(size_t)col*HW_] = ux | (uy << 16);                            \
    }                                                                   \
  } while(0)
  EPILOG(acc_s0, acc_gx0, acc_gy0, c_x0, c_y0, hb);
  EPILOG(acc_s1, acc_gx1, acc_gy1, c_x1, c_y1, hb+1);
  #undef EPILOG
}

// ---------------------------------------------------------------------------
// Sampler: one WG per (b,co); f16 score plane in LDS; coords/out streamed.
// Grid 1024 XCD-swizzled (matches conv's b->XCD mapping, L2-hot reads).
// ---------------------------------------------------------------------------
__global__ __launch_bounds__(256, 4) void k_sample(
    const ushort_t* __restrict__ score, const unsigned int* __restrict__ coords,
    float* __restrict__ out){
  int bid = blockIdx.x;
  int idx = bid >> 3;
  int b  = (bid & 7) + 8*(idx >> 6);
  int co = idx & 63;
  int t = threadIdx.x;
  __shared__ __align__(16) ushort_t SC[128*136];

  const ushort_t* sp = score + (size_t)(b*64 + co)*HW_;
  #pragma unroll
  for (int i=0;i<8;i++){
    int c = i*256 + t;
    int y = c >> 4; int xg = (c & 15)*8;
    *(f16x8*)&SC[y*136 + xg] = *(const f16x8*)(sp + c*8);
  }
  __syncthreads();

  const unsigned int* cp = coords + (size_t)(b*64 + co)*HW_;
  float* op = out + (size_t)(b*64 + co)*HW_;
  uint4v ca = *(const uint4v*)(cp + t*8);
  uint4v cb2 = *(const uint4v*)(cp + t*8 + 4);
  #pragma unroll 1
  for (int k=0;k<8;k++){
    int px = (k*256 + t)*8;
    uint4v na, nb;
    if (k < 7){
      na = *(const uint4v*)(cp + px + 2048);
      nb = *(const uint4v*)(cp + px + 2052);
    }
    float r[8];
    #pragma unroll
    for (int j=0;j<8;j++){
      unsigned u = (j < 4) ? ca[j] : cb2[j-4];
      float ix = (float)(u & 0xffffu)*(1.0f/480.0f) - 2.0f;
      float iy = (float)(u >> 16)   *(1.0f/480.0f) - 2.0f;
      float x0f = floorf(ix), y0f = floorf(iy);
      int x0 = (int)x0f, y0 = (int)y0f;
      float wx1 = ix - x0f, wy1 = iy - y0f;
      float wx0 = 1.f - wx1, wy0 = 1.f - wy1;
      int x0c = min(max(x0,0),127), x1c = min(max(x0+1,0),127);
      int y0c = min(max(y0,0),127), y1c = min(max(y0+1,0),127);
      bool vx0 = (unsigned)x0     < 128u, vx1 = (unsigned)(x0+1) < 128u;
      bool vy0 = (unsigned)y0     < 128u, vy1 = (unsigned)(y0+1) < 128u;
      float v00 = (vy0 && vx0) ? h_bits2f(SC[y0c*136 + x0c]) : 0.f;
      float v01 = (vy0 && vx1) ? h_bits2f(SC[y0c*136 + x1c]) : 0.f;
      float v10 = (vy1 && vx0) ? h_bits2f(SC[y1c*136 + x0c]) : 0.f;
      float v11 = (vy1 && vx1) ? h_bits2f(SC[y1c*136 + x1c]) : 0.f;
      r[j] = v00*(wy0*wx0) + v01*(wy0*wx1) + v10*(wy1*wx0) + v11*(wy1*wx1);
    }
    f32x4 r0 = {r[0],r[1],r[2],r[3]};
    f32x4 r1 = {r[4],r[5],r[6],r[7]};
    *(f32x4*)(op + px)     = r0;
    *(f32x4*)(op + px + 4) = r1;
    ca = na; cb2 = nb;
  }
}

// ---------------------------------------------------------------------------
extern "C" void kernel_launch(void* const* d_in, const int* in_sizes, int n_in,
                              void* d_out, int out_size, void* d_ws, size_t ws_size,
                              hipStream_t stream){
  const float* x  = (const float*)d_in[0];
  const float* Ws = (const float*)d_in[1];
  const float* bs = (const float*)d_in[2];
  const float* Wx = (const float*)d_in[3];
  const float* bx = (const float*)d_in[4];
  const float* Wy = (const float*)d_in[5];
  const float* by = (const float*)d_in[6];
  float* out = (float*)d_out;
  ushort_t* ws  = (ushort_t*)d_ws;
  ushort_t*     score  = ws;                                   // 33.5 MB f16
  unsigned int* coords = (unsigned int*)(ws + 16777216);       // 67.1 MB u32
  ushort_t*     WpH    = ws + 50331648;                        // 221 KB
  unsigned int* WpC    = (unsigned int*)(ws + 50331648 + 110592); // 147 KB

  k_repack  <<<dim3(576),  256, 0, stream>>>(Ws, Wx, Wy, WpH, WpC);
  k_conv_all<<<dim3(1024), 512, 0, stream>>>(x, WpH, WpC, bs, bx, by, score, coords);
  k_sample  <<<dim3(1024), 256, 0, stream>>>(score, coords, out);
}

// Round 7
// 258.841 us; speedup vs baseline: 1.1713x; 1.0786x over previous
//
#include <hip/hip_runtime.h>
#include <stdint.h>

typedef unsigned short ushort_t;
typedef _Float16 f16x8 __attribute__((ext_vector_type(8)));
typedef float f32x4 __attribute__((ext_vector_type(4)));
typedef float f32x16 __attribute__((ext_vector_type(16)));
typedef int   i32x4 __attribute__((ext_vector_type(4)));
typedef int   i32x16 __attribute__((ext_vector_type(16)));
typedef unsigned int uint4v __attribute__((ext_vector_type(4)));

#define HW_ 16384
#define MFMAH  __builtin_amdgcn_mfma_f32_32x32x16_f16
#define MFMAI8 __builtin_amdgcn_mfma_i32_32x32x32_i8
#define C_CORR (1.0f/16777216.0f)   // 2^-24: Al8(2^15)*Wh8(2^9) and Ah8(2^4)*Wl8(2^20)

__device__ __forceinline__ ushort_t f2h_bits(float f){
  union { _Float16 h; ushort_t u; } c; c.h = (_Float16)f; return c.u;
}
__device__ __forceinline__ float h_bits2f(ushort_t u){
  union { _Float16 h; ushort_t u; } c; c.u = u; return (float)c.h;
}
__device__ __forceinline__ int clamp8(int v){ return min(max(v,-127),127); }

// ---------------------------------------------------------------------------
// WpH (f16 bits): ((conv*2+mh)*36 + ks16)*512 + lane*8 + j
//   conv 0=Ws 1=Wx 2=Wy; co = mh*32+(lane&31); tap = ks16>>2;
//   ci = (ks16&3)*16 + (lane>>5)*8 + j.
// WpC (i8 dwords): ((g*2+mh)*18 + ks32)*256 + lane*4 + j4
//   g 0=Wh8x 1=Wh8y 2=Wl8x 3=Wl8y; tap = ks32>>1;
//   ci = (ks32&1)*32 + (lane>>5)*16 + j4*4 + bb.
// ---------------------------------------------------------------------------
__global__ __launch_bounds__(256) void k_repack(
    const float* __restrict__ Ws, const float* __restrict__ Wx,
    const float* __restrict__ Wy,
    ushort_t* __restrict__ WpH, unsigned int* __restrict__ WpC){
  int e = blockIdx.x*256 + threadIdx.x;
  if (e < 110592){
    int j = e & 7; int lane = (e >> 3) & 63; int rest = e >> 9;
    int ks = rest % 36; int cm = rest / 36;
    int conv = cm >> 1; int mh = cm & 1;
    int co = mh*32 + (lane & 31);
    int tap = ks >> 2;
    int ci = (ks & 3)*16 + ((lane >> 5) & 1)*8 + j;
    const float* src = (conv==0) ? Ws : (conv==1) ? Wx : Wy;
    WpH[e] = f2h_bits(src[(co*64 + ci)*9 + tap]);
  } else if (e < 110592 + 36864){
    int d = e - 110592;
    int j4 = d & 3; int lane = (d >> 2) & 63; int rest = d >> 8;
    int ks = rest % 18; int gm = rest / 18;
    int g = gm >> 1; int mh = gm & 1;
    int co = mh*32 + (lane & 31);
    int tap = ks >> 1;
    const float* src = (g==0 || g==2) ? Wx : Wy;
    unsigned dd = 0;
    #pragma unroll
    for (int bb=0; bb<4; bb++){
      int ci = (ks & 1)*32 + ((lane >> 5) & 1)*16 + j4*4 + bb;
      float w = src[(co*64 + ci)*9 + tap];
      int v;
      if (g < 2){
        v = clamp8((int)rintf(w*512.f));
      } else {
        float wl = w - h_bits2f(f2h_bits(w));
        v = clamp8((int)rintf(wl*1048576.f));
      }
      dd |= ((unsigned)(v & 255)) << (bb*8);
    }
    WpC[d] = dd;
  }
}

// ---------------------------------------------------------------------------
// Fused conv. R6 post-mortem: 3.9x less weight L2 traffic -> flat (153us).
// All volume/occupancy theories dead. Per-SIMD math: MFMA pipe work = 92K
// cyc vs 367K wall -> 73% memory wait, ~1-2K cyc exposed PER ITERATION --
// far above L2-hit latency. New theory: the 98MB/dispatch score+coords
// WRITE stream (12MB per XCD vs 4MB L2) continuously evicts the 368KB
// weight set, turning every weight load into an L3/HBM-class miss.
// Fix: NON-TEMPORAL stores for score/coords (evict-first, stop thrashing
// weights). Conv loop / LDS / regs / grid byte-identical to R6.
// LDS [10][34][64] x {f16,i8,i8} = 87 KB -> 1 block/CU, 8 waves/CU.
// Grid 1024 XCD-swizzled: all WGs of batch b on XCD b&7.
// ---------------------------------------------------------------------------
__global__ __launch_bounds__(512, 2) void k_conv_all(
    const float* __restrict__ x,
    const ushort_t* __restrict__ WpH, const unsigned int* __restrict__ WpC,
    const float* __restrict__ bs, const float* __restrict__ bx,
    const float* __restrict__ by,
    ushort_t* __restrict__ score, unsigned int* __restrict__ coords){
  int bid = blockIdx.x;
  int idx = bid >> 3;
  int b = (bid & 7) + 8*(idx >> 6);     // 64 blocks per batch
  int rest = idx & 63;
  int h0 = (rest >> 2)*8;               // 16 h-tiles of 8 rows
  int wq = (rest & 3)*32;
  int t = threadIdx.x; int lane = t & 63; int wid = t >> 6;   // wid 0..7
  int n = lane & 31; int kh = lane >> 5;
  __shared__ __align__(16) _Float16 BH[10*34*64];   // 43520 B
  __shared__ __align__(16) char BAl[10*34*64];      // 21760 B
  __shared__ __align__(16) char BAh[10*34*64];      // 21760 B

  // ---- staging: 1360 items of 16 ci (10 rows x 4 q x 34 w1), 3 passes ----
  const float* xb = x + (size_t)b*64*HW_;
  #pragma unroll
  for (int it=0; it<3; it++){
    int f = it*512 + t;
    if (f < 1360){
      int r = f/136; int rem = f - r*136; int q = rem/34; int w1 = rem - q*34;
      int y = h0 + r - 1; int w = wq + w1 - 1;
      f16x8 h0v = {0,0,0,0,0,0,0,0}, h1v = {0,0,0,0,0,0,0,0};
      unsigned alb[4] = {0,0,0,0}, ahb[4] = {0,0,0,0};
      if (((unsigned)y < 128u) & ((unsigned)w < 128u)){
        const float* p = xb + (size_t)(q*16)*HW_ + y*128 + w;
        #pragma unroll
        for (int j=0; j<16; j++){
          float v = p[(size_t)j*HW_];
          _Float16 hv = (_Float16)v;
          float al = v - (float)hv;
          int a8 = clamp8((int)rintf(al*32768.f));
          int x8 = clamp8((int)rintf(v*16.f));
          if (j < 8) h0v[j] = hv; else h1v[j-8] = hv;
          alb[j>>2] |= ((unsigned)(a8 & 255)) << ((j&3)*8);
          ahb[j>>2] |= ((unsigned)(x8 & 255)) << ((j&3)*8);
        }
      }
      int base = (r*34 + w1)*64;
      int sw = w1 & 7;
      *(f16x8*)&BH[base + (((2*q)   ^ sw) << 3)] = h0v;
      *(f16x8*)&BH[base + (((2*q+1) ^ sw) << 3)] = h1v;
      int islot = ((q + (w1 >> 1)) & 3) << 4;
      i32x4 av  = {(int)alb[0],(int)alb[1],(int)alb[2],(int)alb[3]};
      i32x4 hv2 = {(int)ahb[0],(int)ahb[1],(int)ahb[2],(int)ahb[3]};
      *(i32x4*)&BAl[base + islot] = av;
      *(i32x4*)&BAh[base + islot] = hv2;
    }
  }
  __syncthreads();

  int mh = wid & 1;      // co half
  int pp = wid >> 1;     // row-pair within tile (0..3)

  f32x16 acc_s0, acc_gx0, acc_gy0, acc_s1, acc_gx1, acc_gy1;
  i32x16 c_x0, c_y0, c_x1, c_y1;
  #pragma unroll
  for (int r2=0; r2<16; r2++){
    acc_s0[r2]=0.f; acc_gx0[r2]=0.f; acc_gy0[r2]=0.f;
    acc_s1[r2]=0.f; acc_gx1[r2]=0.f; acc_gy1[r2]=0.f;
    c_x0[r2]=0; c_y0[r2]=0; c_x1[r2]=0; c_y1[r2]=0;
  }

  // incremented weight pointers: f16 advance 1024 elem (2 ks16) per ks-iter,
  // i8 advance 1024 B (1 ks32) per ks-iter.
  const ushort_t* pS = WpH + ((0*2+mh)*36)*512 + lane*8;
  const ushort_t* pX = WpH + ((1*2+mh)*36)*512 + lane*8;
  const ushort_t* pY = WpH + ((2*2+mh)*36)*512 + lane*8;
  const char* pWhx = (const char*)WpC + (((0*2+mh)*18)*64 + lane)*16;
  const char* pWhy = (const char*)WpC + (((1*2+mh)*18)*64 + lane)*16;
  const char* pWlx = (const char*)WpC + (((2*2+mh)*18)*64 + lane)*16;
  const char* pWly = (const char*)WpC + (((3*2+mh)*18)*64 + lane)*16;

  // one weight fetch -> MFMAs for BOTH rows of this wave's pair
  #define ROWBLK(ROWB, AS_, AX_, AY_, CX_, CY_) do {                    \
    f16x8 bA  = *(const f16x8*)&BH[(ROWB) + off0];                      \
    f16x8 bB  = *(const f16x8*)&BH[(ROWB) + off1];                      \
    i32x4 bal = *(const i32x4*)&BAl[(ROWB) + islot];                    \
    i32x4 bah = *(const i32x4*)&BAh[(ROWB) + islot];                    \
    AS_ = MFMAH(sA, bA, AS_, 0,0,0);                                    \
    AX_ = MFMAH(xA, bA, AX_, 0,0,0);                                    \
    AY_ = MFMAH(yA, bA, AY_, 0,0,0);                                    \
    AS_ = MFMAH(sB, bB, AS_, 0,0,0);                                    \
    AX_ = MFMAH(xB, bB, AX_, 0,0,0);                                    \
    AY_ = MFMAH(yB, bB, AY_, 0,0,0);                                    \
    CX_ = MFMAI8(whx, bal, CX_, 0,0,0);                                 \
    CX_ = MFMAI8(wlx, bah, CX_, 0,0,0);                                 \
    CY_ = MFMAI8(why, bal, CY_, 0,0,0);                                 \
    CY_ = MFMAI8(wly, bah, CY_, 0,0,0);                                 \
  } while(0)

  #pragma unroll 1
  for (int ks=0; ks<18; ++ks){
    int tap = ks >> 1; int qp = ks & 1;
    int rb = tap/3; int dw = tap - rb*3 - 1;
    int w1 = n + dw + 1;                    // 0..33
    int sw = w1 & 7;
    int rowb0 = ((rb + 2*pp)*34 + w1)*64;   // LDS row for output row 2*pp
    int rowb1 = rowb0 + 34*64;              // output row 2*pp+1
    int off0  = ((qp*4 + kh)     ^ sw) << 3;
    int off1  = ((qp*4 + 2 + kh) ^ sw) << 3;
    int islot = (((qp*2 + kh) + (w1 >> 1)) & 3) << 4;
    f16x8 sA = *(const f16x8*)pS;
    f16x8 sB = *(const f16x8*)(pS + 512);
    f16x8 xA = *(const f16x8*)pX;
    f16x8 xB = *(const f16x8*)(pX + 512);
    f16x8 yA = *(const f16x8*)pY;
    f16x8 yB = *(const f16x8*)(pY + 512);
    i32x4 whx = *(const i32x4*)pWhx;
    i32x4 why = *(const i32x4*)pWhy;
    i32x4 wlx = *(const i32x4*)pWlx;
    i32x4 wly = *(const i32x4*)pWly;
    ROWBLK(rowb0, acc_s0, acc_gx0, acc_gy0, c_x0, c_y0);
    ROWBLK(rowb1, acc_s1, acc_gx1, acc_gy1, c_x1, c_y1);
    pS += 1024; pX += 1024; pY += 1024;
    pWhx += 1024; pWhy += 1024; pWlx += 1024; pWly += 1024;
  }
  #undef ROWBLK

  // epilogue: score f16 + packed u16 coords (step 1/480 px, clamp [-2,129])
  // NON-TEMPORAL stores: evict-first policy so the 98MB write stream stops
  // flushing the 368KB weight set out of each XCD's 4MB L2.
  int w = wq + n;
  int hb = h0 + 2*pp;
  #define EPILOG(AS_, AX_, AY_, CX_, CY_, H_) do {                      \
    ushort_t*     sb = score  + (size_t)b*64*HW_ + (H_)*128 + w;        \
    unsigned int* cb = coords + (size_t)b*64*HW_ + (H_)*128 + w;        \
    _Pragma("unroll")                                                   \
    for (int reg=0; reg<16; reg++){                                     \
      int col = mh*32 + (reg & 3) + 8*(reg >> 2) + 4*kh;                \
      float sv = AS_[reg] + bs[col];                                    \
      float gx = AX_[reg] + (float)CX_[reg]*C_CORR + bx[col];           \
      float gy = AY_[reg] + (float)CY_[reg]*C_CORR + by[col];           \
      __builtin_nontemporal_store(f2h_bits(sv), &sb[(size_t)col*HW_]);  \
      float ixf = fminf(fmaxf((gx + 1.f)*64.f - 0.5f, -2.f), 129.f);    \
      float iyf = fminf(fmaxf((gy + 1.f)*64.f - 0.5f, -2.f), 129.f);    \
      unsigned ux = (unsigned)rintf((ixf + 2.f)*480.f);                 \
      unsigned uy = (unsigned)rintf((iyf + 2.f)*480.f);                 \
      __builtin_nontemporal_store(ux | (uy << 16), &cb[(size_t)col*HW_]); \
    }                                                                   \
  } while(0)
  EPILOG(acc_s0, acc_gx0, acc_gy0, c_x0, c_y0, hb);
  EPILOG(acc_s1, acc_gx1, acc_gy1, c_x1, c_y1, hb+1);
  #undef EPILOG
}

// ---------------------------------------------------------------------------
// Sampler: one WG per (b,co); f16 score plane in LDS; coords/out streamed.
// All global traffic is read-once/write-once -> non-temporal throughout.
// Grid 1024 XCD-swizzled (matches conv's b->XCD mapping).
// ---------------------------------------------------------------------------
__global__ __launch_bounds__(256, 4) void k_sample(
    const ushort_t* __restrict__ score, const unsigned int* __restrict__ coords,
    float* __restrict__ out){
  int bid = blockIdx.x;
  int idx = bid >> 3;
  int b  = (bid & 7) + 8*(idx >> 6);
  int co = idx & 63;
  int t = threadIdx.x;
  __shared__ __align__(16) ushort_t SC[128*136];

  const ushort_t* sp = score + (size_t)(b*64 + co)*HW_;
  #pragma unroll
  for (int i=0;i<8;i++){
    int c = i*256 + t;
    int y = c >> 4; int xg = (c & 15)*8;
    *(f16x8*)&SC[y*136 + xg] =
        __builtin_nontemporal_load((const f16x8*)(sp + c*8));
  }
  __syncthreads();

  const unsigned int* cp = coords + (size_t)(b*64 + co)*HW_;
  float* op = out + (size_t)(b*64 + co)*HW_;
  uint4v ca  = __builtin_nontemporal_load((const uint4v*)(cp + t*8));
  uint4v cb2 = __builtin_nontemporal_load((const uint4v*)(cp + t*8 + 4));
  #pragma unroll 1
  for (int k=0;k<8;k++){
    int px = (k*256 + t)*8;
    uint4v na, nb;
    if (k < 7){
      na = __builtin_nontemporal_load((const uint4v*)(cp + px + 2048));
      nb = __builtin_nontemporal_load((const uint4v*)(cp + px + 2052));
    }
    float r[8];
    #pragma unroll
    for (int j=0;j<8;j++){
      unsigned u = (j < 4) ? ca[j] : cb2[j-4];
      float ix = (float)(u & 0xffffu)*(1.0f/480.0f) - 2.0f;
      float iy = (float)(u >> 16)   *(1.0f/480.0f) - 2.0f;
      float x0f = floorf(ix), y0f = floorf(iy);
      int x0 = (int)x0f, y0 = (int)y0f;
      float wx1 = ix - x0f, wy1 = iy - y0f;
      float wx0 = 1.f - wx1, wy0 = 1.f - wy1;
      int x0c = min(max(x0,0),127), x1c = min(max(x0+1,0),127);
      int y0c = min(max(y0,0),127), y1c = min(max(y0+1,0),127);
      bool vx0 = (unsigned)x0     < 128u, vx1 = (unsigned)(x0+1) < 128u;
      bool vy0 = (unsigned)y0     < 128u, vy1 = (unsigned)(y0+1) < 128u;
      float v00 = (vy0 && vx0) ? h_bits2f(SC[y0c*136 + x0c]) : 0.f;
      float v01 = (vy0 && vx1) ? h_bits2f(SC[y0c*136 + x1c]) : 0.f;
      float v10 = (vy1 && vx0) ? h_bits2f(SC[y1c*136 + x0c]) : 0.f;
      float v11 = (vy1 && vx1) ? h_bits2f(SC[y1c*136 + x1c]) : 0.f;
      r[j] = v00*(wy0*wx0) + v01*(wy0*wx1) + v10*(wy1*wx0) + v11*(wy1*wx1);
    }
    f32x4 r0 = {r[0],r[1],r[2],r[3]};
    f32x4 r1 = {r[4],r[5],r[6],r[7]};
    __builtin_nontemporal_store(r0, (f32x4*)(op + px));
    __builtin_nontemporal_store(r1, (f32x4*)(op + px + 4));
    ca = na; cb2 = nb;
  }
}

// ---------------------------------------------------------------------------
extern "C" void kernel_launch(void* const* d_in, const int* in_sizes, int n_in,
                              void* d_out, int out_size, void* d_ws, size_t ws_size,
                              hipStream_t stream){
  const float* x  = (const float*)d_in[0];
  const float* Ws = (const float*)d_in[1];
  const float* bs = (const float*)d_in[2];
  const float* Wx = (const float*)d_in[3];
  const float* bx = (const float*)d_in[4];
  const float* Wy = (const float*)d_in[5];
  const float* by = (const float*)d_in[6];
  float* out = (float*)d_out;
  ushort_t* ws  = (ushort_t*)d_ws;
  ushort_t*     score  = ws;                                   // 33.5 MB f16
  unsigned int* coords = (unsigned int*)(ws + 16777216);       // 67.1 MB u32
  ushort_t*     WpH    = ws + 50331648;                        // 221 KB
  unsigned int* WpC    = (unsigned int*)(ws + 50331648 + 110592); // 147 KB

  k_repack  <<<dim3(576),  256, 0, stream>>>(Ws, Wx, Wy, WpH, WpC);
  k_conv_all<<<dim3(1024), 512, 0, stream>>>(x, WpH, WpC, bs, bx, by, score, coords);
  k_sample  <<<dim3(1024), 256, 0, stream>>>(score, coords, out);
}